// Round 2
// baseline (1634.845 us; speedup 1.0000x reference)
//
#include <hip/hip_runtime.h>

#define N_NODES 100000
#define E_EDGES 3200000
#define IN_F 128
#define ATT 128
#define HEADS 8
#define DK 16
#define SLOPE 0.2f
#define NH (N_NODES * HEADS)   // 800000
#define NXCD 8

// True hardware XCD id (0..7 on MI355X), wave-uniform. [measured: learn_hip m09]
__device__ __forceinline__ int get_xcc() {
    int x;
    asm volatile("s_getreg_b32 %0, hwreg(HW_REG_XCC_ID, 0, 4)" : "=s"(x));
    return x & (NXCD - 1);
}

// ---------------------------------------------------------------------------
// K1: wx = x @ W   (100000x128 @ 128x128, fp32 vector FMA)
//     + fused epilogue: s_src[n][h] = sum_k wx[n][h*16+k]*a1[k], s_dst with a2
// ---------------------------------------------------------------------------
__global__ __launch_bounds__(256) void gemm_s_kernel(
    const float* __restrict__ x, const float* __restrict__ W,
    const float* __restrict__ a, float* __restrict__ wx,
    float* __restrict__ s_src, float* __restrict__ s_dst)
{
    __shared__ float xs[8][128];   // [k][row] transposed x tile
    __shared__ float Ws[8][128];   // [k][col]

    const int tid = threadIdx.x;
    const int ty  = tid >> 4;      // 0..15  -> row group (8 rows)
    const int tx  = tid & 15;      // 0..15  -> col group (8 cols)
    const int row0 = blockIdx.x * 128;

    float acc[8][8];
#pragma unroll
    for (int i = 0; i < 8; i++)
#pragma unroll
        for (int j = 0; j < 8; j++) acc[i][j] = 0.f;

    const int lrow  = tid >> 1;        // 0..127 row for x staging
    const int khalf = (tid & 1) * 4;   // 0 or 4
    const int wkk   = tid >> 5;        // 0..7 k-row for W staging
    const int wc    = (tid & 31) * 4;  // col*4

    for (int k0 = 0; k0 < IN_F; k0 += 8) {
        float4 xv = make_float4(0.f, 0.f, 0.f, 0.f);
        const int grow = row0 + lrow;
        if (grow < N_NODES)
            xv = *(const float4*)(x + (size_t)grow * IN_F + k0 + khalf);
        const float4 wv = *(const float4*)(W + (size_t)(k0 + wkk) * ATT + wc);

        __syncthreads();   // previous iter's reads done
        xs[khalf + 0][lrow] = xv.x;
        xs[khalf + 1][lrow] = xv.y;
        xs[khalf + 2][lrow] = xv.z;
        xs[khalf + 3][lrow] = xv.w;
        *(float4*)(&Ws[wkk][wc]) = wv;
        __syncthreads();

#pragma unroll
        for (int kk = 0; kk < 8; kk++) {
            float av[8], bv[8];
            *(float4*)(av)     = *(const float4*)(&xs[kk][ty * 8]);
            *(float4*)(av + 4) = *(const float4*)(&xs[kk][ty * 8 + 4]);
            *(float4*)(bv)     = *(const float4*)(&Ws[kk][tx * 8]);
            *(float4*)(bv + 4) = *(const float4*)(&Ws[kk][tx * 8 + 4]);
#pragma unroll
            for (int r = 0; r < 8; r++)
#pragma unroll
                for (int c = 0; c < 8; c++)
                    acc[r][c] = fmaf(av[r], bv[c], acc[r][c]);
        }
    }

    const int koff = (tx & 1) * 8;
    const int head = tx >> 1;
    float a1[8], a2[8];
#pragma unroll
    for (int c = 0; c < 8; c++) {
        a1[c] = a[koff + c];
        a2[c] = a[DK + koff + c];
    }

#pragma unroll
    for (int r = 0; r < 8; r++) {
        const int grow = row0 + ty * 8 + r;
        const bool ok = (grow < N_NODES);
        if (ok) {
            *(float4*)(wx + (size_t)grow * ATT + tx * 8) =
                make_float4(acc[r][0], acc[r][1], acc[r][2], acc[r][3]);
            *(float4*)(wx + (size_t)grow * ATT + tx * 8 + 4) =
                make_float4(acc[r][4], acc[r][5], acc[r][6], acc[r][7]);
        }
        float p1 = 0.f, p2 = 0.f;
#pragma unroll
        for (int c = 0; c < 8; c++) {
            p1 = fmaf(acc[r][c], a1[c], p1);
            p2 = fmaf(acc[r][c], a2[c], p2);
        }
        p1 += __shfl_xor(p1, 1);
        p2 += __shfl_xor(p2, 1);
        if (((tx & 1) == 0) && ok) {
            s_src[(size_t)grow * HEADS + head] = p1;
            s_dst[(size_t)grow * HEADS + head] = p2;
        }
    }
}

// ---------------------------------------------------------------------------
// K2: per-edge exp(leakyrelu(score)) accumulated into this XCD's private
// denom copy via WORKGROUP-scope atomics (serviced in local L2, no memory-
// side write-through). Copies are disjoint per XCD -> no cross-XCD aliasing.
// ---------------------------------------------------------------------------
__global__ __launch_bounds__(256) void denom_kernel(
    const int* __restrict__ src, const int* __restrict__ dst,
    const float* __restrict__ s_src, const float* __restrict__ s_dst,
    float* __restrict__ denoms)
{
    float* mydenom = denoms + (size_t)get_xcc() * NH;
    const int e = blockIdx.x * 256 + threadIdx.x;
    if (e >= E_EDGES) return;
    const int s = src[e];
    const int d = dst[e];
    const float4* ps = (const float4*)(s_src + (size_t)s * HEADS);
    const float4* pd = (const float4*)(s_dst + (size_t)d * HEADS);
    const float4 s0 = ps[0], s1 = ps[1], d0 = pd[0], d1 = pd[1];
    float sc[8] = {s0.x + d0.x, s0.y + d0.y, s0.z + d0.z, s0.w + d0.w,
                   s1.x + d1.x, s1.y + d1.y, s1.z + d1.z, s1.w + d1.w};
    float* base = mydenom + (size_t)s * HEADS;
#pragma unroll
    for (int h = 0; h < 8; h++) {
        float v = sc[h];
        v = v > 0.f ? v : SLOPE * v;
        __hip_atomic_fetch_add(base + h, __expf(v),
                               __ATOMIC_RELAXED, __HIP_MEMORY_SCOPE_WORKGROUP);
    }
}

// ---------------------------------------------------------------------------
// K2b: rdenom[i] = 1 / sum_c denoms[c][i]  (written into copy 0)
// ---------------------------------------------------------------------------
__global__ __launch_bounds__(256) void reduce_recip_kernel(float* __restrict__ denoms)
{
    const int i = blockIdx.x * 256 + threadIdx.x;
    if (i >= NH) return;
    float s = 0.f;
#pragma unroll
    for (int c = 0; c < NXCD; c++) s += denoms[(size_t)c * NH + i];
    denoms[i] = __frcp_rn(s);
}

// ---------------------------------------------------------------------------
// K3: attention[e][h] = exp(leakyrelu(score)) * rdenom[src][h]
// ---------------------------------------------------------------------------
__global__ __launch_bounds__(256) void norm_kernel(
    const int* __restrict__ src, const int* __restrict__ dst,
    const float* __restrict__ s_src, const float* __restrict__ s_dst,
    const float* __restrict__ rdenom, float* __restrict__ att)
{
    const int e = blockIdx.x * 256 + threadIdx.x;
    if (e >= E_EDGES) return;
    const int s = src[e];
    const int d = dst[e];
    const float4* ps = (const float4*)(s_src + (size_t)s * HEADS);
    const float4* pd = (const float4*)(s_dst + (size_t)d * HEADS);
    const float4 s0 = ps[0], s1 = ps[1], d0 = pd[0], d1 = pd[1];
    const float4* pr = (const float4*)(rdenom + (size_t)s * HEADS);
    const float4 r0 = pr[0], r1 = pr[1];
    float sc[8] = {s0.x + d0.x, s0.y + d0.y, s0.z + d0.z, s0.w + d0.w,
                   s1.x + d1.x, s1.y + d1.y, s1.z + d1.z, s1.w + d1.w};
    float rd[8] = {r0.x, r0.y, r0.z, r0.w, r1.x, r1.y, r1.z, r1.w};
    float o[8];
#pragma unroll
    for (int h = 0; h < 8; h++) {
        float v = sc[h];
        v = v > 0.f ? v : SLOPE * v;
        o[h] = __expf(v) * rd[h];
    }
    float4* po = (float4*)(att + (size_t)e * HEADS);
    po[0] = make_float4(o[0], o[1], o[2], o[3]);
    po[1] = make_float4(o[4], o[5], o[6], o[7]);
}

extern "C" void kernel_launch(void* const* d_in, const int* in_sizes, int n_in,
                              void* d_out, int out_size, void* d_ws, size_t ws_size,
                              hipStream_t stream)
{
    const float* x    = (const float*)d_in[0];
    const int*   edge = (const int*)d_in[1];
    const float* W    = (const float*)d_in[2];
    const float* a    = (const float*)d_in[3];

    float* out = (float*)d_out;
    float* att = out;                                 // (E, HEADS)
    float* wx  = out + (size_t)E_EDGES * HEADS;       // (N, ATT)

    float* ws     = (float*)d_ws;
    float* s_src  = ws;                               // NH floats
    float* s_dst  = s_src + (size_t)NH;               // NH floats
    float* denoms = s_dst + (size_t)NH;               // NXCD * NH floats (25.6 MB)

    const int* src = edge;                 // edge[0][0][:]
    const int* dst = edge + E_EDGES;       // edge[0][1][:]

    hipMemsetAsync(denoms, 0, (size_t)NXCD * NH * sizeof(float), stream);

    const int gemm_blocks = (N_NODES + 127) / 128;    // 782
    gemm_s_kernel<<<gemm_blocks, 256, 0, stream>>>(x, W, a, wx, s_src, s_dst);

    const int eblocks = (E_EDGES + 255) / 256;        // 12500
    denom_kernel<<<eblocks, 256, 0, stream>>>(src, dst, s_src, s_dst, denoms);

    const int nblocks = (NH + 255) / 256;
    reduce_recip_kernel<<<nblocks, 256, 0, stream>>>(denoms);

    norm_kernel<<<eblocks, 256, 0, stream>>>(src, dst, s_src, s_dst, denoms, att);
}

// Round 3
// 822.039 us; speedup vs baseline: 1.9888x; 1.9888x over previous
//
#include <hip/hip_runtime.h>

#define N_NODES 100000
#define E_EDGES 3200000
#define IN_F 128
#define ATT 128
#define HEADS 8
#define DK 16
#define SLOPE 0.2f
#define NH (N_NODES * HEADS)   // 800000

// LDS-binned denom reduction parameters
#define CHUNK 2048                                   // nodes per LDS bin (64 KB)
#define NCHUNK ((N_NODES + CHUNK - 1) / CHUNK)       // 49
#define NSPLIT 10                                    // edge splits (private copies)
#define SCAN_THREADS 512

// ---------------------------------------------------------------------------
// K1: wx = x @ W   (100000x128 @ 128x128, fp32 vector FMA)
//     + fused epilogue: s_src[n][h] = sum_k wx[n][h*16+k]*a1[k], s_dst with a2
// ---------------------------------------------------------------------------
__global__ __launch_bounds__(256) void gemm_s_kernel(
    const float* __restrict__ x, const float* __restrict__ W,
    const float* __restrict__ a, float* __restrict__ wx,
    float* __restrict__ s_src, float* __restrict__ s_dst)
{
    __shared__ float xs[8][128];   // [k][row] transposed x tile
    __shared__ float Ws[8][128];   // [k][col]

    const int tid = threadIdx.x;
    const int ty  = tid >> 4;      // 0..15  -> row group (8 rows)
    const int tx  = tid & 15;      // 0..15  -> col group (8 cols)
    const int row0 = blockIdx.x * 128;

    float acc[8][8];
#pragma unroll
    for (int i = 0; i < 8; i++)
#pragma unroll
        for (int j = 0; j < 8; j++) acc[i][j] = 0.f;

    const int lrow  = tid >> 1;        // 0..127 row for x staging
    const int khalf = (tid & 1) * 4;   // 0 or 4
    const int wkk   = tid >> 5;        // 0..7 k-row for W staging
    const int wc    = (tid & 31) * 4;  // col*4

    for (int k0 = 0; k0 < IN_F; k0 += 8) {
        float4 xv = make_float4(0.f, 0.f, 0.f, 0.f);
        const int grow = row0 + lrow;
        if (grow < N_NODES)
            xv = *(const float4*)(x + (size_t)grow * IN_F + k0 + khalf);
        const float4 wv = *(const float4*)(W + (size_t)(k0 + wkk) * ATT + wc);

        __syncthreads();   // previous iter's reads done
        xs[khalf + 0][lrow] = xv.x;
        xs[khalf + 1][lrow] = xv.y;
        xs[khalf + 2][lrow] = xv.z;
        xs[khalf + 3][lrow] = xv.w;
        *(float4*)(&Ws[wkk][wc]) = wv;
        __syncthreads();

#pragma unroll
        for (int kk = 0; kk < 8; kk++) {
            float av[8], bv[8];
            *(float4*)(av)     = *(const float4*)(&xs[kk][ty * 8]);
            *(float4*)(av + 4) = *(const float4*)(&xs[kk][ty * 8 + 4]);
            *(float4*)(bv)     = *(const float4*)(&Ws[kk][tx * 8]);
            *(float4*)(bv + 4) = *(const float4*)(&Ws[kk][tx * 8 + 4]);
#pragma unroll
            for (int r = 0; r < 8; r++)
#pragma unroll
                for (int c = 0; c < 8; c++)
                    acc[r][c] = fmaf(av[r], bv[c], acc[r][c]);
        }
    }

    const int koff = (tx & 1) * 8;
    const int head = tx >> 1;
    float a1[8], a2[8];
#pragma unroll
    for (int c = 0; c < 8; c++) {
        a1[c] = a[koff + c];
        a2[c] = a[DK + koff + c];
    }

#pragma unroll
    for (int r = 0; r < 8; r++) {
        const int grow = row0 + ty * 8 + r;
        const bool ok = (grow < N_NODES);
        if (ok) {
            *(float4*)(wx + (size_t)grow * ATT + tx * 8) =
                make_float4(acc[r][0], acc[r][1], acc[r][2], acc[r][3]);
            *(float4*)(wx + (size_t)grow * ATT + tx * 8 + 4) =
                make_float4(acc[r][4], acc[r][5], acc[r][6], acc[r][7]);
        }
        float p1 = 0.f, p2 = 0.f;
#pragma unroll
        for (int c = 0; c < 8; c++) {
            p1 = fmaf(acc[r][c], a1[c], p1);
            p2 = fmaf(acc[r][c], a2[c], p2);
        }
        p1 += __shfl_xor(p1, 1);
        p2 += __shfl_xor(p2, 1);
        if (((tx & 1) == 0) && ok) {
            s_src[(size_t)grow * HEADS + head] = p1;
            s_dst[(size_t)grow * HEADS + head] = p2;
        }
    }
}

// ---------------------------------------------------------------------------
// K2: LDS-binned denom. Block (chunk, split) scans edge range [e0,e1) and
// accumulates exp(leakyrelu(score)) into a 64 KB LDS bin for its node chunk
// (ds_add_f32 atomics). Flush -> denoms[split][chunk region] (no global
// atomics anywhere).
// ---------------------------------------------------------------------------
__global__ __launch_bounds__(SCAN_THREADS) void denom_scan_kernel(
    const int* __restrict__ src, const int* __restrict__ dst,
    const float* __restrict__ s_src, const float* __restrict__ s_dst,
    float* __restrict__ denoms)   // [NSPLIT][NH]
{
    __shared__ float acc[CHUNK * HEADS];   // 64 KB

    const int chunk = blockIdx.x;
    const int split = blockIdx.y;
    const int lo = chunk * CHUNK;
    const int hi = min(lo + CHUNK, N_NODES);

    for (int i = threadIdx.x; i < CHUNK * HEADS; i += SCAN_THREADS)
        acc[i] = 0.f;
    __syncthreads();

    const int per_split = E_EDGES / NSPLIT;          // 320000, divisible by 4
    const int e0 = split * per_split;
    const int e1 = e0 + per_split;

    for (int e = e0 + threadIdx.x * 4; e < e1; e += SCAN_THREADS * 4) {
        const int4 s4 = *(const int4*)(src + e);
        const int ss[4] = {s4.x, s4.y, s4.z, s4.w};
#pragma unroll
        for (int j = 0; j < 4; j++) {
            const int s = ss[j];
            if (s >= lo && s < hi) {
                const int d = dst[e + j];
                const float4* ps = (const float4*)(s_src + (size_t)s * HEADS);
                const float4* pd = (const float4*)(s_dst + (size_t)d * HEADS);
                const float4 a0 = ps[0], a1 = ps[1], b0 = pd[0], b1 = pd[1];
                const float sc[8] = {a0.x + b0.x, a0.y + b0.y, a0.z + b0.z, a0.w + b0.w,
                                     a1.x + b1.x, a1.y + b1.y, a1.z + b1.z, a1.w + b1.w};
                float* base = acc + (s - lo) * HEADS;
#pragma unroll
                for (int h = 0; h < 8; h++) {
                    float v = sc[h];
                    v = v > 0.f ? v : SLOPE * v;
                    atomicAdd(base + h, __expf(v));   // ds_add_f32
                }
            }
        }
    }
    __syncthreads();

    // flush chunk bin to this split's private copy (coalesced float4 stores)
    float* outp = denoms + (size_t)split * NH + (size_t)lo * HEADS;
    const int cnt = (hi - lo) * HEADS;               // divisible by 4
    for (int i = threadIdx.x * 4; i < cnt; i += SCAN_THREADS * 4)
        *(float4*)(outp + i) = *(const float4*)(acc + i);
}

// ---------------------------------------------------------------------------
// K2b: rdenom[i] = 1 / sum_c denoms[c][i]  (written into copy 0)
// ---------------------------------------------------------------------------
__global__ __launch_bounds__(256) void reduce_recip_kernel(float* __restrict__ denoms)
{
    const int i = blockIdx.x * 256 + threadIdx.x;
    if (i >= NH) return;
    float s = 0.f;
#pragma unroll
    for (int c = 0; c < NSPLIT; c++) s += denoms[(size_t)c * NH + i];
    denoms[i] = __frcp_rn(s);
}

// ---------------------------------------------------------------------------
// K3: attention[e][h] = exp(leakyrelu(score)) * rdenom[src][h]
// ---------------------------------------------------------------------------
__global__ __launch_bounds__(256) void norm_kernel(
    const int* __restrict__ src, const int* __restrict__ dst,
    const float* __restrict__ s_src, const float* __restrict__ s_dst,
    const float* __restrict__ rdenom, float* __restrict__ att)
{
    const int e = blockIdx.x * 256 + threadIdx.x;
    if (e >= E_EDGES) return;
    const int s = src[e];
    const int d = dst[e];
    const float4* ps = (const float4*)(s_src + (size_t)s * HEADS);
    const float4* pd = (const float4*)(s_dst + (size_t)d * HEADS);
    const float4 s0 = ps[0], s1 = ps[1], d0 = pd[0], d1 = pd[1];
    const float4* pr = (const float4*)(rdenom + (size_t)s * HEADS);
    const float4 r0 = pr[0], r1 = pr[1];
    float sc[8] = {s0.x + d0.x, s0.y + d0.y, s0.z + d0.z, s0.w + d0.w,
                   s1.x + d1.x, s1.y + d1.y, s1.z + d1.z, s1.w + d1.w};
    float rd[8] = {r0.x, r0.y, r0.z, r0.w, r1.x, r1.y, r1.z, r1.w};
    float o[8];
#pragma unroll
    for (int h = 0; h < 8; h++) {
        float v = sc[h];
        v = v > 0.f ? v : SLOPE * v;
        o[h] = __expf(v) * rd[h];
    }
    float4* po = (float4*)(att + (size_t)e * HEADS);
    po[0] = make_float4(o[0], o[1], o[2], o[3]);
    po[1] = make_float4(o[4], o[5], o[6], o[7]);
}

extern "C" void kernel_launch(void* const* d_in, const int* in_sizes, int n_in,
                              void* d_out, int out_size, void* d_ws, size_t ws_size,
                              hipStream_t stream)
{
    const float* x    = (const float*)d_in[0];
    const int*   edge = (const int*)d_in[1];
    const float* W    = (const float*)d_in[2];
    const float* a    = (const float*)d_in[3];

    float* out = (float*)d_out;
    float* att = out;                                 // (E, HEADS)
    float* wx  = out + (size_t)E_EDGES * HEADS;       // (N, ATT)

    float* ws     = (float*)d_ws;
    float* s_src  = ws;                               // NH floats
    float* s_dst  = s_src + (size_t)NH;               // NH floats
    float* denoms = s_dst + (size_t)NH;               // NSPLIT * NH floats (32 MB)

    const int* src = edge;                 // edge[0][0][:]
    const int* dst = edge + E_EDGES;       // edge[0][1][:]

    const int gemm_blocks = (N_NODES + 127) / 128;    // 782
    gemm_s_kernel<<<gemm_blocks, 256, 0, stream>>>(x, W, a, wx, s_src, s_dst);

    dim3 sgrid(NCHUNK, NSPLIT);                       // 49 x 10
    denom_scan_kernel<<<sgrid, SCAN_THREADS, 0, stream>>>(src, dst, s_src, s_dst, denoms);

    const int nblocks = (NH + 255) / 256;
    reduce_recip_kernel<<<nblocks, 256, 0, stream>>>(denoms);

    const int eblocks = (E_EDGES + 255) / 256;        // 12500
    norm_kernel<<<eblocks, 256, 0, stream>>>(src, dst, s_src, s_dst, denoms, att);
}

// Round 4
// 657.515 us; speedup vs baseline: 2.4864x; 1.2502x over previous
//
#include <hip/hip_runtime.h>

#define N_NODES 100000
#define E_EDGES 3200000
#define IN_F 128
#define ATT 128
#define HEADS 8
#define DK 16
#define SLOPE 0.2f
#define NH (N_NODES * HEADS)   // 800000

// LDS-binned denom reduction parameters
#define CHUNK 1792
#define NCHUNK 56                       // 56*1792 = 100352 >= N
#define NSPLIT 9                        // grid = 504 blocks = co-resident at 2/CU
#define QCAP 1016
#define SCAN_THREADS 512
#define ROUND_EDGES (SCAN_THREADS * 32) // 16384 edges per round

// ---------------------------------------------------------------------------
// K1: wx = x @ W   (100000x128 @ 128x128, fp32 vector FMA)
//     + fused epilogue: s_src[n][h] = sum_k wx[n][h*16+k]*a1[k], s_dst with a2
// ---------------------------------------------------------------------------
__global__ __launch_bounds__(256) void gemm_s_kernel(
    const float* __restrict__ x, const float* __restrict__ W,
    const float* __restrict__ a, float* __restrict__ wx,
    float* __restrict__ s_src, float* __restrict__ s_dst)
{
    __shared__ float xs[8][128];   // [k][row] transposed x tile
    __shared__ float Ws[8][128];   // [k][col]

    const int tid = threadIdx.x;
    const int ty  = tid >> 4;      // 0..15  -> row group (8 rows)
    const int tx  = tid & 15;      // 0..15  -> col group (8 cols)
    const int row0 = blockIdx.x * 128;

    float acc[8][8];
#pragma unroll
    for (int i = 0; i < 8; i++)
#pragma unroll
        for (int j = 0; j < 8; j++) acc[i][j] = 0.f;

    const int lrow  = tid >> 1;        // 0..127 row for x staging
    const int khalf = (tid & 1) * 4;   // 0 or 4
    const int wkk   = tid >> 5;        // 0..7 k-row for W staging
    const int wc    = (tid & 31) * 4;  // col*4

    for (int k0 = 0; k0 < IN_F; k0 += 8) {
        float4 xv = make_float4(0.f, 0.f, 0.f, 0.f);
        const int grow = row0 + lrow;
        if (grow < N_NODES)
            xv = *(const float4*)(x + (size_t)grow * IN_F + k0 + khalf);
        const float4 wv = *(const float4*)(W + (size_t)(k0 + wkk) * ATT + wc);

        __syncthreads();   // previous iter's reads done
        xs[khalf + 0][lrow] = xv.x;
        xs[khalf + 1][lrow] = xv.y;
        xs[khalf + 2][lrow] = xv.z;
        xs[khalf + 3][lrow] = xv.w;
        *(float4*)(&Ws[wkk][wc]) = wv;
        __syncthreads();

#pragma unroll
        for (int kk = 0; kk < 8; kk++) {
            float av[8], bv[8];
            *(float4*)(av)     = *(const float4*)(&xs[kk][ty * 8]);
            *(float4*)(av + 4) = *(const float4*)(&xs[kk][ty * 8 + 4]);
            *(float4*)(bv)     = *(const float4*)(&Ws[kk][tx * 8]);
            *(float4*)(bv + 4) = *(const float4*)(&Ws[kk][tx * 8 + 4]);
#pragma unroll
            for (int r = 0; r < 8; r++)
#pragma unroll
                for (int c = 0; c < 8; c++)
                    acc[r][c] = fmaf(av[r], bv[c], acc[r][c]);
        }
    }

    const int koff = (tx & 1) * 8;
    const int head = tx >> 1;
    float a1[8], a2[8];
#pragma unroll
    for (int c = 0; c < 8; c++) {
        a1[c] = a[koff + c];
        a2[c] = a[DK + koff + c];
    }

#pragma unroll
    for (int r = 0; r < 8; r++) {
        const int grow = row0 + ty * 8 + r;
        const bool ok = (grow < N_NODES);
        if (ok) {
            *(float4*)(wx + (size_t)grow * ATT + tx * 8) =
                make_float4(acc[r][0], acc[r][1], acc[r][2], acc[r][3]);
            *(float4*)(wx + (size_t)grow * ATT + tx * 8 + 4) =
                make_float4(acc[r][4], acc[r][5], acc[r][6], acc[r][7]);
        }
        float p1 = 0.f, p2 = 0.f;
#pragma unroll
        for (int c = 0; c < 8; c++) {
            p1 = fmaf(acc[r][c], a1[c], p1);
            p2 = fmaf(acc[r][c], a2[c], p2);
        }
        p1 += __shfl_xor(p1, 1);
        p2 += __shfl_xor(p2, 1);
        if (((tx & 1) == 0) && ok) {
            s_src[(size_t)grow * HEADS + head] = p1;
            s_dst[(size_t)grow * HEADS + head] = p2;
        }
    }
}

// ---------------------------------------------------------------------------
// K2: LDS-binned denom with ballot-compaction.
// Block (chunk, split): scan split's edges in 16K rounds, compact hits
// (src in [lo,hi)) into an LDS queue, then drain the queue DENSE (all lanes
// active). acc is head-major padded: bank = (node+head) % 32 -> conflict-free.
// Flush transposes to node-major global copy. No global atomics anywhere.
// ---------------------------------------------------------------------------
__global__ __launch_bounds__(SCAN_THREADS) void denom_scan_kernel(
    const int* __restrict__ src, const int* __restrict__ dst,
    const float* __restrict__ s_src, const float* __restrict__ s_dst,
    float* __restrict__ denoms)   // [NSPLIT][NH]
{
    __shared__ float acc[HEADS][CHUNK + 1];   // 57376 B
    __shared__ int qs[QCAP];                  // 4064 B
    __shared__ int qe[QCAP];                  // 4064 B
    __shared__ int qc;

    const int t    = threadIdx.x;
    const int lane = t & 63;
    const int lo   = blockIdx.x * CHUNK;
    const int hi   = min(lo + CHUNK, N_NODES);
    const int split = blockIdx.y;

    for (int i = t; i < HEADS * (CHUNK + 1); i += SCAN_THREADS)
        ((float*)acc)[i] = 0.f;
    if (t == 0) qc = 0;
    __syncthreads();

    const int per_split = (E_EDGES + NSPLIT - 1) / NSPLIT;  // 355556 (div 4)
    const int e0 = split * per_split;
    const int e1 = min(e0 + per_split, E_EDGES);
    const int nrounds = (e1 - e0 + ROUND_EDGES - 1) / ROUND_EDGES;

    for (int r = 0; r < nrounds; r++) {
        const int rb = e0 + r * ROUND_EDGES;
#pragma unroll
        for (int u = 0; u < 8; u++) {
            const int e4 = rb + (u * SCAN_THREADS + t) * 4;
            int4 s4 = make_int4(-1, -1, -1, -1);
            if (e4 < e1) s4 = *(const int4*)(src + e4);
            const int ss[4] = {s4.x, s4.y, s4.z, s4.w};
#pragma unroll
            for (int j = 0; j < 4; j++) {
                const int s = ss[j];
                const bool hit = (s >= lo) && (s < hi);
                const unsigned long long m = __ballot(hit);
                if (m) {
                    const int leader = __ffsll((long long)m) - 1;
                    int wb = 0;
                    if (lane == leader) wb = atomicAdd(&qc, __popcll(m));
                    wb = __shfl(wb, leader);
                    if (hit) {
                        const int idx = wb + __popcll(m & ((1ull << lane) - 1ull));
                        if (idx < QCAP) { qs[idx] = s; qe[idx] = e4 + j; }
                        else {
                            // statistically unreachable overflow fallback
                            const int d = dst[e4 + j];
                            const float4* ps = (const float4*)(s_src + (size_t)s * HEADS);
                            const float4* pd = (const float4*)(s_dst + (size_t)d * HEADS);
                            const float4 a0 = ps[0], a1 = ps[1], b0 = pd[0], b1 = pd[1];
                            const float sc[8] = {a0.x + b0.x, a0.y + b0.y, a0.z + b0.z, a0.w + b0.w,
                                                 a1.x + b1.x, a1.y + b1.y, a1.z + b1.z, a1.w + b1.w};
#pragma unroll
                            for (int h = 0; h < 8; h++) {
                                float v = sc[h];
                                v = v > 0.f ? v : SLOPE * v;
                                atomicAdd(&acc[h][s - lo], __expf(v));
                            }
                        }
                    }
                }
            }
        }
        __syncthreads();
        const int nq = min(qc, QCAP);
        for (int base = 0; base < nq; base += SCAN_THREADS) {
            const int i = base + t;
            if (i < nq) {
                const int s = qs[i];
                const int d = dst[qe[i]];
                const float4* ps = (const float4*)(s_src + (size_t)s * HEADS);
                const float4* pd = (const float4*)(s_dst + (size_t)d * HEADS);
                const float4 a0 = ps[0], a1 = ps[1], b0 = pd[0], b1 = pd[1];
                const float sc[8] = {a0.x + b0.x, a0.y + b0.y, a0.z + b0.z, a0.w + b0.w,
                                     a1.x + b1.x, a1.y + b1.y, a1.z + b1.z, a1.w + b1.w};
#pragma unroll
                for (int h = 0; h < 8; h++) {
                    float v = sc[h];
                    v = v > 0.f ? v : SLOPE * v;
                    atomicAdd(&acc[h][s - lo], __expf(v));   // ds_add_f32
                }
            }
        }
        __syncthreads();
        if (t == 0) qc = 0;
        __syncthreads();
    }

    // flush: transpose LDS head-major -> global node-major private copy
    const int cnt = (hi - lo) * HEADS;
    float* outp = denoms + (size_t)split * NH + (size_t)lo * HEADS;
    for (int i = t; i < cnt; i += SCAN_THREADS)
        outp[i] = acc[i & 7][i >> 3];
}

// ---------------------------------------------------------------------------
// K2b: rdenom[i] = 1 / sum_c denoms[c][i]  (written into copy 0)
// ---------------------------------------------------------------------------
__global__ __launch_bounds__(256) void reduce_recip_kernel(float* __restrict__ denoms)
{
    const int i = blockIdx.x * 256 + threadIdx.x;
    if (i >= NH) return;
    float s = 0.f;
#pragma unroll
    for (int c = 0; c < NSPLIT; c++) s += denoms[(size_t)c * NH + i];
    denoms[i] = __frcp_rn(s);
}

// ---------------------------------------------------------------------------
// K3: attention[e][h] = exp(leakyrelu(score)) * rdenom[src][h]
// ---------------------------------------------------------------------------
__global__ __launch_bounds__(256) void norm_kernel(
    const int* __restrict__ src, const int* __restrict__ dst,
    const float* __restrict__ s_src, const float* __restrict__ s_dst,
    const float* __restrict__ rdenom, float* __restrict__ att)
{
    const int e = blockIdx.x * 256 + threadIdx.x;
    if (e >= E_EDGES) return;
    const int s = src[e];
    const int d = dst[e];
    const float4* ps = (const float4*)(s_src + (size_t)s * HEADS);
    const float4* pd = (const float4*)(s_dst + (size_t)d * HEADS);
    const float4 s0 = ps[0], s1 = ps[1], d0 = pd[0], d1 = pd[1];
    const float4* pr = (const float4*)(rdenom + (size_t)s * HEADS);
    const float4 r0 = pr[0], r1 = pr[1];
    float sc[8] = {s0.x + d0.x, s0.y + d0.y, s0.z + d0.z, s0.w + d0.w,
                   s1.x + d1.x, s1.y + d1.y, s1.z + d1.z, s1.w + d1.w};
    float rd[8] = {r0.x, r0.y, r0.z, r0.w, r1.x, r1.y, r1.z, r1.w};
    float o[8];
#pragma unroll
    for (int h = 0; h < 8; h++) {
        float v = sc[h];
        v = v > 0.f ? v : SLOPE * v;
        o[h] = __expf(v) * rd[h];
    }
    float4* po = (float4*)(att + (size_t)e * HEADS);
    po[0] = make_float4(o[0], o[1], o[2], o[3]);
    po[1] = make_float4(o[4], o[5], o[6], o[7]);
}

extern "C" void kernel_launch(void* const* d_in, const int* in_sizes, int n_in,
                              void* d_out, int out_size, void* d_ws, size_t ws_size,
                              hipStream_t stream)
{
    const float* x    = (const float*)d_in[0];
    const int*   edge = (const int*)d_in[1];
    const float* W    = (const float*)d_in[2];
    const float* a    = (const float*)d_in[3];

    float* out = (float*)d_out;
    float* att = out;                                 // (E, HEADS)
    float* wx  = out + (size_t)E_EDGES * HEADS;       // (N, ATT)

    float* ws     = (float*)d_ws;
    float* s_src  = ws;                               // NH floats
    float* s_dst  = s_src + (size_t)NH;               // NH floats
    float* denoms = s_dst + (size_t)NH;               // NSPLIT * NH floats (28.8 MB)

    const int* src = edge;                 // edge[0][0][:]
    const int* dst = edge + E_EDGES;       // edge[0][1][:]

    const int gemm_blocks = (N_NODES + 127) / 128;    // 782
    gemm_s_kernel<<<gemm_blocks, 256, 0, stream>>>(x, W, a, wx, s_src, s_dst);

    dim3 sgrid(NCHUNK, NSPLIT);                       // 56 x 9 = 504 blocks
    denom_scan_kernel<<<sgrid, SCAN_THREADS, 0, stream>>>(src, dst, s_src, s_dst, denoms);

    const int nblocks = (NH + 255) / 256;
    reduce_recip_kernel<<<nblocks, 256, 0, stream>>>(denoms);

    const int eblocks = (E_EDGES + 255) / 256;        // 12500
    norm_kernel<<<eblocks, 256, 0, stream>>>(src, dst, s_src, s_dst, denoms, att);
}